// Round 5
// baseline (153.874 us; speedup 1.0000x reference)
//
#include <hip/hip_runtime.h>

#define T      64     // num_thetas
#define S      32     // bump_steps
#define NGRAPH 64
#define NSPLIT 16     // blocks per graph -> 1024 blocks
#define NW     4      // waves per block

// Phase 1: block b handles slice (b % 16) of graph (b / 16) (node range via
// binary search on sorted batch). Saturation trick: scaled logit step
// d = 100*2.2/31 ~= 7.1 => only s in {s*-1, s*, s*+1} need exact sigmoids
// (dropped tails <= 8.2e-4/node); s >= s*+2 contribute exactly 1.0 ->
// "ones-start" histogram + prefix sum. Partials go to ws[b][32][64] with
// PLAIN stores — zero global atomics anywhere.
__global__ __launch_bounds__(256, 8) void ect_partial(
    const float* __restrict__ x, const float* __restrict__ v,
    const float* __restrict__ lin, const int* __restrict__ batch,
    float* __restrict__ ws, int n_points)
{
    __shared__ float acc[T * 33];   // [t][s] exact sigmoids; col 32 = OOB trash
    __shared__ float hist[T * 33];  // [t][c] ones-start counts; col 32 = never
    __shared__ float tot[T * 5];    // [t][wave] partials, stride 5 anti-conflict

    const int tid = threadIdx.x;
    const int t   = tid & 63;       // lane == theta
    const int w   = tid >> 6;      // wave id
    const int b   = blockIdx.x;
    const int g   = b >> 4;        // graph
    const int c   = b & (NSPLIT - 1);

    for (int i = tid; i < T * 33; i += 256) { acc[i] = 0.0f; hist[i] = 0.0f; }

    // lower_bound(g) and lower_bound(g+1), two independent chains interleaved
    int lo0 = 0, hi0 = n_points, lo1 = 0, hi1 = n_points;
#pragma unroll 1
    for (int it = 0; it < 17; ++it) {             // 2^17 > 65536
        const int m0 = (lo0 + hi0) >> 1;
        const int m1 = (lo1 + hi1) >> 1;
        const int b0 = (lo0 < hi0) ? batch[m0] : 0;
        const int b1 = (lo1 < hi1) ? batch[m1] : 0;
        if (lo0 < hi0) { if (b0 <  g) lo0 = m0 + 1; else hi0 = m0; }
        if (lo1 < hi1) { if (b1 <= g) lo1 = m1 + 1; else hi1 = m1; }
    }
    const int len = lo1 - lo0;
    const int n0  = lo0 + (len * c) / NSPLIT;
    const int n1  = lo0 + (len * (c + 1)) / NSPLIT;

    const float lin0     = lin[0];
    const float step     = lin[1] - lin0;
    const float inv_step = 1.0f / step;
    const float K2 = (100.0f * step) * 1.4426950408889634f;  // ~10.24
    const float r  = __builtin_amdgcn_exp2f(-K2);

    const float v0 = v[0 * T + t];
    const float v1 = v[1 * T + t];
    const float v2 = v[2 * T + t];

    __syncthreads();

#pragma unroll 2
    for (int n = n0 + w; n < n1; n += NW) {
        const float* xp = x + 3 * n;              // wave-uniform address
        const float nh = xp[0] * v0 + xp[1] * v1 + xp[2] * v2;
        const float f  = (nh - lin0) * inv_step;
        const float fs = ceilf(f);
        const int   ss = (int)fs;                 // s*: first s with lin_s>=nh
        const float gg = fs - f;                  // [0,1)
        float e = __builtin_amdgcn_exp2f(K2 * (1.0f - gg));  // exp(-z) at ss-1
#pragma unroll
        for (int j = 0; j < 3; j++) {             // s = ss-1, ss, ss+1
            const int   s   = ss - 1 + j;
            const float sig = __builtin_amdgcn_rcpf(1.0f + e);
            const bool  ok  = ((unsigned)s < 32u);
            __hip_atomic_fetch_add(&acc[t * 33 + (ok ? s : 32)],
                                   ok ? sig : 0.0f,
                                   __ATOMIC_RELAXED, __HIP_MEMORY_SCOPE_WORKGROUP);
            e *= r;
        }
        const int cc = min(max(ss + 2, 0), 32);   // ones start (32 = never)
        __hip_atomic_fetch_add(&hist[t * 33 + cc], 1.0f,
                               __ATOMIC_RELAXED, __HIP_MEMORY_SCOPE_WORKGROUP);
    }
    __syncthreads();

    // flush: ones(s) = prefix(hist); ws[b][s][t] = acc + ones (plain stores)
    float h[8], sumA = 0.0f;
#pragma unroll
    for (int j = 0; j < 8; j++) { h[j] = hist[t * 33 + 8 * w + j]; sumA += h[j]; }
    tot[t * 5 + w] = sumA;
    __syncthreads();

    float run = 0.0f;
    for (int q = 0; q < w; q++) run += tot[t * 5 + q];
    float* wsb = ws + (size_t)b * (S * T);
#pragma unroll
    for (int j = 0; j < 8; j++) {
        run += h[j];                              // inclusive prefix
        const int s = 8 * w + j;
        wsb[s * T + t] = acc[t * 33 + s] + run;
    }
}

// Phase 2: out[g][i] = sum over 16 slice-partials. Plain stores cover the
// whole output -> no memset needed.
__global__ __launch_bounds__(256) void ect_reduce(
    const float* __restrict__ ws, float* __restrict__ out)
{
    const int idx = blockIdx.x * 256 + threadIdx.x;  // [0, 64*2048)
    const int g   = idx >> 11;
    const int i   = idx & 2047;
    float sum = 0.0f;
#pragma unroll
    for (int c = 0; c < NSPLIT; c++)
        sum += ws[(size_t)(g * NSPLIT + c) * (S * T) + i];
    out[idx] = sum;
}

extern "C" void kernel_launch(void* const* d_in, const int* in_sizes, int n_in,
                              void* d_out, int out_size, void* d_ws, size_t ws_size,
                              hipStream_t stream) {
    const float* x     = (const float*)d_in[0];   // [N,3]
    const float* v     = (const float*)d_in[1];   // [3,64]
    const float* lin   = (const float*)d_in[2];   // [32]
    const int*   batch = (const int*)d_in[3];     // [N], sorted
    float* out = (float*)d_out;                   // [64,32,64]
    float* ws  = (float*)d_ws;                    // 1024 * 2048 floats = 8 MB

    const int n_points = in_sizes[0] / 3;

    ect_partial<<<NGRAPH * NSPLIT, 256, 0, stream>>>(x, v, lin, batch, ws, n_points);
    ect_reduce<<<NGRAPH * S * T / 256, 256, 0, stream>>>(ws, out);
}

// Round 6
// 91.276 us; speedup vs baseline: 1.6858x; 1.6858x over previous
//
#include <hip/hip_runtime.h>

#define T      64     // num_thetas
#define S      32     // bump_steps
#define NGRAPH 64
#define NSPLIT 16     // slices per graph -> 1024 blocks
#define SPT    8      // s-values per thread; wave w owns s-group [8w, 8w+8)

// Phase 1: block b = (graph g, slice c). Node range via binary search on the
// sorted batch. Wave w covers s-group w for ALL slice nodes; lane = theta.
// Geometric-chain sigmoid (R3 body, proven absmax 4.0): ONE exp2 + 8 rcp per
// node per wave; accumulators live in 8 VGPRs per thread. Each (s,t) is owned
// by exactly one thread -> flush = plain coalesced store to ws[b][s][t].
// ZERO atomics of any scope, ZERO LDS.
__global__ __launch_bounds__(256, 8) void ect_partial(
    const float* __restrict__ x, const float* __restrict__ v,
    const float* __restrict__ lin, const int* __restrict__ batch,
    float* __restrict__ ws, int n_points)
{
    const int tid = threadIdx.x;
    const int t   = tid & 63;       // lane == theta
    const int w   = tid >> 6;       // wave id == s-group
    const int b   = blockIdx.x;
    const int g   = b >> 4;         // graph
    const int c   = b & (NSPLIT - 1);

    // lower_bound(g) and lower_bound(g+1), two chains interleaved
    int lo0 = 0, hi0 = n_points, lo1 = 0, hi1 = n_points;
#pragma unroll 1
    for (int it = 0; it < 17; ++it) {             // 2^17 > 65536
        const int m0 = (lo0 + hi0) >> 1;
        const int m1 = (lo1 + hi1) >> 1;
        const int b0 = (lo0 < hi0) ? batch[m0] : 0;
        const int b1 = (lo1 < hi1) ? batch[m1] : 0;
        if (lo0 < hi0) { if (b0 <  g) lo0 = m0 + 1; else hi0 = m0; }
        if (lo1 < hi1) { if (b1 <= g) lo1 = m1 + 1; else hi1 = m1; }
    }
    const int len = lo1 - lo0;
    const int n0  = lo0 + (len * c) / NSPLIT;
    const int n1  = lo0 + (len * (c + 1)) / NSPLIT;

    const float K  = 144.26950408889634f;               // 100 * log2(e)
    const float c0 = lin[w * SPT] * K;                  // this wave's first threshold
    const float m  = __builtin_amdgcn_exp2f((lin[0] - lin[1]) * K); // exp(-100*step) < 1

    const float v0 = v[0 * T + t];
    const float v1 = v[1 * T + t];
    const float v2 = v[2 * T + t];

    float acc[SPT];
#pragma unroll
    for (int j = 0; j < SPT; j++) acc[j] = 0.0f;

#pragma unroll 2
    for (int n = n0; n < n1; n++) {
        const float* xp = x + 3 * n;                    // block-uniform address
        const float nh = xp[0] * v0 + xp[1] * v1 + xp[2] * v2;
        float e = __builtin_amdgcn_exp2f(nh * K - c0);  // window span 57 ln-units:
#pragma unroll                                          // inf/0 saturate correctly
        for (int j = 0; j < SPT; j++) {
            acc[j] += __builtin_amdgcn_rcpf(1.0f + e);  // sigmoid(100*(lin_s - nh))
            e *= m;
        }
    }

    // flush: plain coalesced stores, each (s,t) owned by one thread
    float* wsb = ws + (size_t)b * (S * T) + (w * SPT) * T + t;
#pragma unroll
    for (int j = 0; j < SPT; j++) wsb[j * T] = acc[j];
}

// Phase 2: out[g][i] = sum of 16 slice partials (plain stores; covers zeroing)
__global__ __launch_bounds__(256) void ect_reduce(
    const float* __restrict__ ws, float* __restrict__ out)
{
    const int idx = blockIdx.x * 256 + threadIdx.x;  // [0, 64*2048)
    const int g   = idx >> 11;
    const int i   = idx & 2047;
    float sum = 0.0f;
#pragma unroll
    for (int c = 0; c < NSPLIT; c++)
        sum += ws[(size_t)(g * NSPLIT + c) * (S * T) + i];
    out[idx] = sum;
}

extern "C" void kernel_launch(void* const* d_in, const int* in_sizes, int n_in,
                              void* d_out, int out_size, void* d_ws, size_t ws_size,
                              hipStream_t stream) {
    const float* x     = (const float*)d_in[0];   // [N,3]
    const float* v     = (const float*)d_in[1];   // [3,64]
    const float* lin   = (const float*)d_in[2];   // [32]
    const int*   batch = (const int*)d_in[3];     // [N], sorted
    float* out = (float*)d_out;                   // [64,32,64]
    float* ws  = (float*)d_ws;                    // 1024 * 2048 floats = 8 MB

    const int n_points = in_sizes[0] / 3;

    ect_partial<<<NGRAPH * NSPLIT, 256, 0, stream>>>(x, v, lin, batch, ws, n_points);
    ect_reduce<<<NGRAPH * S * T / 256, 256, 0, stream>>>(ws, out);
}